// Round 1
// baseline (906.971 us; speedup 1.0000x reference)
//
#include <hip/hip_runtime.h>
#include <math.h>

#define NB 8
#define LQ 900
#define DM 256
#define NH 8
#define DH 32
#define NL 4
#define NP 4
#define DFFN 1024
#define LIN 13294
#define NVAL (NB*LIN)      // 106352 rows for value projection
#define MROW (NB*LQ)       // 7200 rows for query-side matmuls

// ---------------- elementwise add (float4) ----------------
__global__ __launch_bounds__(256) void add_kernel(const float* __restrict__ a,
                                                  const float* __restrict__ b,
                                                  float* __restrict__ c, int n4) {
  int i = blockIdx.x * 256 + threadIdx.x;
  if (i < n4) {
    float4 x = ((const float4*)a)[i];
    float4 y = ((const float4*)b)[i];
    ((float4*)c)[i] = make_float4(x.x + y.x, x.y + y.y, x.z + y.z, x.w + y.w);
  }
}

// ---------------- generic fp32 GEMM: C = (A@W + bias)*scale, opt relu ----------------
// A: (M,K) row-major, W: (K,N) row-major, bias: (N,)
// tile 64x64, BK=16, block 256 threads, 4x4 microtile per thread
__global__ __launch_bounds__(256) void gemm_kernel(const float* __restrict__ A,
                                                   const float* __restrict__ W,
                                                   const float* __restrict__ bias,
                                                   float* __restrict__ C,
                                                   int M, int Nn, int K, float scale, int relu) {
  __shared__ float As[16][68];   // [k][m], padded to 68 floats (16B-aligned rows, ~2-way bank)
  __shared__ float Ws[16][64];   // [k][n]
  const int tid = threadIdx.x;
  const int tx = tid & 15, ty = tid >> 4;
  const int m0 = blockIdx.y << 6, n0 = blockIdx.x << 6;
  const int ar = tid >> 2, ac = (tid & 3) << 2;       // A tile: row ar, cols ac..ac+3
  const int wr = tid >> 4, wn = (tid & 15) << 2;      // W tile: row wr, cols wn..wn+3
  float acc[4][4] = {};
  for (int kt = 0; kt < K; kt += 16) {
    float4 av = make_float4(0.f, 0.f, 0.f, 0.f);
    const int arow = m0 + ar;
    if (arow < M) av = *(const float4*)(A + (size_t)arow * K + kt + ac);
    As[ac + 0][ar] = av.x; As[ac + 1][ar] = av.y; As[ac + 2][ar] = av.z; As[ac + 3][ar] = av.w;
    *(float4*)&Ws[wr][wn] = *(const float4*)(W + (size_t)(kt + wr) * Nn + n0 + wn);
    __syncthreads();
#pragma unroll
    for (int kk = 0; kk < 16; kk++) {
      float4 a4 = *(const float4*)&As[kk][ty << 2];
      float4 b4 = *(const float4*)&Ws[kk][tx << 2];
      float am[4] = {a4.x, a4.y, a4.z, a4.w};
      float bm[4] = {b4.x, b4.y, b4.z, b4.w};
#pragma unroll
      for (int i = 0; i < 4; i++)
#pragma unroll
        for (int j = 0; j < 4; j++)
          acc[i][j] += am[i] * bm[j];
    }
    __syncthreads();
  }
#pragma unroll
  for (int i = 0; i < 4; i++) {
    const int row = m0 + (ty << 2) + i;
    if (row < M) {
#pragma unroll
      for (int j = 0; j < 4; j++) {
        const int col = n0 + (tx << 2) + j;
        float v = (acc[i][j] + bias[col]) * scale;
        if (relu) v = fmaxf(v, 0.f);
        C[(size_t)row * Nn + col] = v;
      }
    }
  }
}

// ---------------- exact flash attention, one thread per query ----------------
// Q,K,V,O: (N, LQ, 256) with head h at channels h*32..h*32+31. Q pre-scaled.
__global__ __launch_bounds__(256) void attn_kernel(const float* __restrict__ Qg,
                                                   const float* __restrict__ Kg,
                                                   const float* __restrict__ Vg,
                                                   float* __restrict__ O) {
  __shared__ float Ks[64][32];
  __shared__ float Vs[64][32];
  const int tid = threadIdx.x;
  const int h = blockIdx.y, b = blockIdx.z;
  const int q = blockIdx.x * 256 + tid;
  const bool qv = q < LQ;
  float qreg[32];
  {
    const float* qp = Qg + ((size_t)(b * LQ + (qv ? q : 0))) * DM + h * DH;
#pragma unroll
    for (int c = 0; c < 32; c += 4) {
      float4 v = *(const float4*)(qp + c);
      qreg[c] = v.x; qreg[c + 1] = v.y; qreg[c + 2] = v.z; qreg[c + 3] = v.w;
    }
  }
  float o[32];
#pragma unroll
  for (int c = 0; c < 32; c++) o[c] = 0.f;
  float m = -INFINITY, lsum = 0.f;
  const int r = tid >> 2, c0 = (tid & 3) << 3;  // each thread stages 1 row x 8 cols
  for (int kt = 0; kt < LQ; kt += 64) {
    const int kr = kt + r;
    const bool rv = kr < LQ;
    const float* kp = Kg + ((size_t)(b * LQ + (rv ? kr : 0))) * DM + h * DH + c0;
    const float* vp = Vg + ((size_t)(b * LQ + (rv ? kr : 0))) * DM + h * DH + c0;
    float4 k0 = make_float4(0, 0, 0, 0), k1 = k0, v0 = k0, v1 = k0;
    if (rv) {
      k0 = ((const float4*)kp)[0]; k1 = ((const float4*)kp)[1];
      v0 = ((const float4*)vp)[0]; v1 = ((const float4*)vp)[1];
    }
    __syncthreads();  // previous tile fully consumed
    ((float4*)&Ks[r][c0])[0] = k0; ((float4*)&Ks[r][c0])[1] = k1;
    ((float4*)&Vs[r][c0])[0] = v0; ((float4*)&Vs[r][c0])[1] = v1;
    __syncthreads();
    const int kn = min(64, LQ - kt);
    float s[64];
#pragma unroll
    for (int j = 0; j < 64; j++) {
      float a = 0.f;
#pragma unroll
      for (int c = 0; c < 32; c++) a += qreg[c] * Ks[j][c];
      s[j] = (j < kn) ? a : -INFINITY;
    }
    float tm = m;
#pragma unroll
    for (int j = 0; j < 64; j++) tm = fmaxf(tm, s[j]);
    const float f = __expf(m - tm);
    lsum *= f;
#pragma unroll
    for (int c = 0; c < 32; c++) o[c] *= f;
#pragma unroll
    for (int j = 0; j < 64; j++) {
      const float p = __expf(s[j] - tm);
      lsum += p;
#pragma unroll
      for (int c = 0; c < 32; c++) o[c] += p * Vs[j][c];
    }
    m = tm;
  }
  if (qv) {
    const float inv = 1.f / lsum;
    float* op = O + ((size_t)(b * LQ + q)) * DM + h * DH;
#pragma unroll
    for (int c = 0; c < 32; c += 4) {
      float4 v;
      v.x = o[c] * inv; v.y = o[c + 1] * inv; v.z = o[c + 2] * inv; v.w = o[c + 3] * inv;
      *(float4*)(op + c) = v;
    }
  }
}

// ---------------- softmax over 16 deform attn weights per (b,q,h) ----------------
__global__ __launch_bounds__(256) void softmax16_kernel(float* __restrict__ att, int n) {
  int t = blockIdx.x * 256 + threadIdx.x;
  if (t >= n) return;
  float* p = att + (size_t)t * 16;
  float v[16];
#pragma unroll
  for (int i = 0; i < 16; i++) v[i] = p[i];
  float m = v[0];
#pragma unroll
  for (int i = 1; i < 16; i++) m = fmaxf(m, v[i]);
  float s = 0.f;
#pragma unroll
  for (int i = 0; i < 16; i++) { v[i] = __expf(v[i] - m); s += v[i]; }
  const float inv = 1.f / s;
#pragma unroll
  for (int i = 0; i < 16; i++) p[i] = v[i] * inv;
}

// ---------------- MS-deform bilinear sampling ----------------
// value: (N, LIN, 256); ref: (N,LQ,4,2); off: (N,LQ,256); att: (N,LQ,128) softmaxed
// out: (N,LQ,256) with channel h*32+d. One thread per output element.
__global__ __launch_bounds__(256) void sample_kernel(const float* __restrict__ value,
                                                     const float* __restrict__ ref,
                                                     const float* __restrict__ off,
                                                     const float* __restrict__ att,
                                                     float* __restrict__ out) {
  const int t = blockIdx.x * 256 + threadIdx.x;  // < NB*LQ*256
  const int d = t & 31;
  const int h = (t >> 5) & 7;
  const int q = (t >> 8) % LQ;
  const int b = t / (LQ * 256);
  const int HLs[4] = {100, 50, 25, 13};
  const int WLs[4] = {100, 50, 25, 13};
  const int STs[4] = {0, 10000, 12500, 13125};
  const float* rp = ref + ((size_t)(b * LQ + q)) * (NL * 2);
  const float* op = off + ((size_t)(b * LQ + q)) * DM + h * (NL * NP * 2);
  const float* ap = att + ((size_t)(b * LQ + q)) * (NH * NL * NP) + h * (NL * NP);
  const float* vb = value + (size_t)b * LIN * DM + h * DH + d;
  float acc = 0.f;
#pragma unroll
  for (int l = 0; l < NL; l++) {
    const int Hl = HLs[l], Wl = WLs[l], st = STs[l];
    const float rx = rp[l * 2], ry = rp[l * 2 + 1];
#pragma unroll
    for (int p = 0; p < NP; p++) {
      const float ox = op[(l * NP + p) * 2], oy = op[(l * NP + p) * 2 + 1];
      const float a = ap[l * NP + p];
      const float locx = rx + ox / (float)Wl;
      const float locy = ry + oy / (float)Hl;
      const float x = locx * (float)Wl - 0.5f;
      const float y = locy * (float)Hl - 0.5f;
      const float xf = floorf(x), yf = floorf(y);
      const float fx = x - xf, fy = y - yf;
      const int x0 = (int)xf, y0 = (int)yf;
      float g00 = 0.f, g10 = 0.f, g01 = 0.f, g11 = 0.f;
      if (y0 >= 0 && y0 < Hl) {
        const float* rowp = vb + (size_t)(st + y0 * Wl) * DM;
        if (x0 >= 0 && x0 < Wl) g00 = rowp[(size_t)x0 * DM];
        if (x0 + 1 >= 0 && x0 + 1 < Wl) g10 = rowp[(size_t)(x0 + 1) * DM];
      }
      if (y0 + 1 >= 0 && y0 + 1 < Hl) {
        const float* rowp = vb + (size_t)(st + (y0 + 1) * Wl) * DM;
        if (x0 >= 0 && x0 < Wl) g01 = rowp[(size_t)x0 * DM];
        if (x0 + 1 >= 0 && x0 + 1 < Wl) g11 = rowp[(size_t)(x0 + 1) * DM];
      }
      acc += a * ((1.f - fx) * (1.f - fy) * g00 + fx * (1.f - fy) * g10 +
                  (1.f - fx) * fy * g01 + fx * fy * g11);
    }
  }
  out[t] = acc;
}

// ---------------- fused residual-add + LayerNorm, wave per row ----------------
__global__ __launch_bounds__(64) void ln_kernel(const float* __restrict__ A,
                                                const float* __restrict__ R,
                                                const float* __restrict__ g,
                                                const float* __restrict__ be,
                                                float* __restrict__ out) {
  const int row = blockIdx.x, t = threadIdx.x;
  const float4 va = ((const float4*)(A + (size_t)row * DM))[t];
  const float4 vr = ((const float4*)(R + (size_t)row * DM))[t];
  const float x0 = va.x + vr.x, x1 = va.y + vr.y, x2 = va.z + vr.z, x3 = va.w + vr.w;
  float s = x0 + x1 + x2 + x3;
  float ss = x0 * x0 + x1 * x1 + x2 * x2 + x3 * x3;
#pragma unroll
  for (int o = 1; o < 64; o <<= 1) { s += __shfl_xor(s, o); ss += __shfl_xor(ss, o); }
  const float mean = s * (1.f / DM);
  const float var = ss * (1.f / DM) - mean * mean;
  const float rstd = rsqrtf(var + 1e-5f);
  const float4 vg = ((const float4*)g)[t];
  const float4 vb = ((const float4*)be)[t];
  float4 o4;
  o4.x = (x0 - mean) * rstd * vg.x + vb.x;
  o4.y = (x1 - mean) * rstd * vg.y + vb.y;
  o4.z = (x2 - mean) * rstd * vg.z + vb.z;
  o4.w = (x3 - mean) * rstd * vg.w + vb.w;
  ((float4*)(out + (size_t)row * DM))[t] = o4;
}

extern "C" void kernel_launch(void* const* d_in, const int* in_sizes, int n_in,
                              void* d_out, int out_size, void* d_ws, size_t ws_size,
                              hipStream_t stream) {
  const float* tgt  = (const float*)d_in[1];
  const float* qpos = (const float*)d_in[2];
  const float* ref  = (const float*)d_in[3];
  const float* src  = (const float*)d_in[4];
  const float* wq = (const float*)d_in[8];  const float* bq = (const float*)d_in[9];
  const float* wk = (const float*)d_in[10]; const float* bk = (const float*)d_in[11];
  const float* wv = (const float*)d_in[12]; const float* bv = (const float*)d_in[13];
  const float* wo = (const float*)d_in[14]; const float* bo = (const float*)d_in[15];
  const float* w_val = (const float*)d_in[16]; const float* b_val = (const float*)d_in[17];
  const float* w_off = (const float*)d_in[18]; const float* b_off = (const float*)d_in[19];
  const float* w_att = (const float*)d_in[20]; const float* b_att = (const float*)d_in[21];
  const float* w_out = (const float*)d_in[22]; const float* b_out = (const float*)d_in[23];
  const float* ln1g = (const float*)d_in[24]; const float* ln1b = (const float*)d_in[25];
  const float* ln2g = (const float*)d_in[26]; const float* ln2b = (const float*)d_in[27];
  const float* ln3g = (const float*)d_in[28]; const float* ln3b = (const float*)d_in[29];
  const float* w1 = (const float*)d_in[30]; const float* b1 = (const float*)d_in[31];
  const float* w2 = (const float*)d_in[32]; const float* b2 = (const float*)d_in[33];

  const size_t S = (size_t)MROW * DM;         // 1,843,200 floats
  const size_t VAL_F = (size_t)NVAL * DM;     // 27,226,112 floats
  float* ws = (float*)d_ws;
  float* value = ws;                // [VAL_F]
  float* B0   = ws + VAL_F;
  float* qin  = B0 + 0 * S;         // later reused as x1
  float* Qb   = B0 + 1 * S;         // later q2, then part of hffn
  float* Kb   = B0 + 2 * S;         // later off
  float* Vb   = B0 + 3 * S;         // later attb
  float* Ob   = B0 + 4 * S;         // later samp
  float* tmp  = B0 + 5 * S;
  float* x1   = B0 + 0 * S;
  float* q2   = B0 + 1 * S;
  float* offb = B0 + 2 * S;
  float* attb = B0 + 3 * S;
  float* samp = B0 + 4 * S;
  float* x2   = B0 + 6 * S;
  float* hffn = B0 + 1 * S;         // 4*S span: [1S,5S)

  const float qscale = 0.17677669529663687f;  // 1/sqrt(32)
  const int n4 = (int)(S / 4);
  const dim3 blk(256);
  const dim3 gAdd((n4 + 255) / 256);
  const dim3 gQ(DM / 64, (MROW + 63) / 64);       // (4,113)
  const dim3 gAtt(2, (MROW + 63) / 64);           // N=128
  const dim3 gVal(DM / 64, (NVAL + 63) / 64);     // (4,1662)
  const dim3 gF1(DFFN / 64, (MROW + 63) / 64);    // (16,113)

  // ---- self-attention ----
  add_kernel<<<gAdd, blk, 0, stream>>>(tgt, qpos, qin, n4);
  gemm_kernel<<<gQ, blk, 0, stream>>>(qin, wq, bq, Qb, MROW, DM, DM, qscale, 0);
  gemm_kernel<<<gQ, blk, 0, stream>>>(qin, wk, bk, Kb, MROW, DM, DM, 1.f, 0);
  gemm_kernel<<<gQ, blk, 0, stream>>>(tgt, wv, bv, Vb, MROW, DM, DM, 1.f, 0);
  attn_kernel<<<dim3((LQ + 255) / 256, NH, NB), blk, 0, stream>>>(Qb, Kb, Vb, Ob);
  gemm_kernel<<<gQ, blk, 0, stream>>>(Ob, wo, bo, tmp, MROW, DM, DM, 1.f, 0);
  ln_kernel<<<dim3(MROW), dim3(64), 0, stream>>>(tmp, tgt, ln2g, ln2b, x1);

  // ---- deformable cross-attention ----
  gemm_kernel<<<gVal, blk, 0, stream>>>(src, w_val, b_val, value, NVAL, DM, DM, 1.f, 0);
  add_kernel<<<gAdd, blk, 0, stream>>>(x1, qpos, q2, n4);
  gemm_kernel<<<gQ, blk, 0, stream>>>(q2, w_off, b_off, offb, MROW, DM, DM, 1.f, 0);
  gemm_kernel<<<gAtt, blk, 0, stream>>>(q2, w_att, b_att, attb, MROW, NH * NL * NP, DM, 1.f, 0);
  softmax16_kernel<<<dim3((MROW * NH + 255) / 256), blk, 0, stream>>>(attb, MROW * NH);
  sample_kernel<<<dim3(MROW), blk, 0, stream>>>(value, ref, offb, attb, samp);
  gemm_kernel<<<gQ, blk, 0, stream>>>(samp, w_out, b_out, tmp, MROW, DM, DM, 1.f, 0);
  ln_kernel<<<dim3(MROW), dim3(64), 0, stream>>>(tmp, x1, ln1g, ln1b, x2);

  // ---- FFN ----
  gemm_kernel<<<gF1, blk, 0, stream>>>(x2, w1, b1, hffn, MROW, DFFN, DM, 1.f, 1);
  gemm_kernel<<<gQ, blk, 0, stream>>>(hffn, w2, b2, tmp, MROW, DM, DFFN, 1.f, 0);
  ln_kernel<<<dim3(MROW), dim3(64), 0, stream>>>(tmp, x2, ln3g, ln3b, (float*)d_out);
}

// Round 2
// 566.160 us; speedup vs baseline: 1.6020x; 1.6020x over previous
//
#include <hip/hip_runtime.h>
#include <math.h>

#define NB 8
#define LQ 900
#define DM 256
#define NH 8
#define DH 32
#define NL 4
#define NP 4
#define DFFN 1024
#define LIN 13294
#define NVAL (NB*LIN)      // 106352 rows for value projection
#define MROW (NB*LQ)       // 7200 rows for query-side matmuls

typedef __attribute__((ext_vector_type(8))) short bf16x8;
typedef __attribute__((ext_vector_type(4))) float f32x4;

__device__ __forceinline__ unsigned short f2bf(float x) {
  unsigned u = __float_as_uint(x);
  u += 0x7FFFu + ((u >> 16) & 1u);   // round-to-nearest-even
  return (unsigned short)(u >> 16);
}

// ---------------- elementwise add (float4) ----------------
__global__ __launch_bounds__(256) void add_kernel(const float* __restrict__ a,
                                                  const float* __restrict__ b,
                                                  float* __restrict__ c, int n4) {
  int i = blockIdx.x * 256 + threadIdx.x;
  if (i < n4) {
    float4 x = ((const float4*)a)[i];
    float4 y = ((const float4*)b)[i];
    ((float4*)c)[i] = make_float4(x.x + y.x, x.y + y.y, x.z + y.z, x.w + y.w);
  }
}

// ---------------- bf16 MFMA GEMM: C = (A@W + bias)*scale, opt relu ----------------
// A: (M,K) fp32 row-major, W: (K,N) fp32 row-major, bias: (N,)
// tile 64x64, BK=32, 256 threads = 4 waves, each wave a 32x32 quadrant (2x2 mfma frags)
#define LDSW 40   // LDS row stride in bf16 elems (80B, 16B-aligned)
__global__ __launch_bounds__(256) void gemm_bf16(const float* __restrict__ A,
                                                 const float* __restrict__ W,
                                                 const float* __restrict__ bias,
                                                 float* __restrict__ C,
                                                 int M, int Nn, int K, float scale, int relu) {
  __shared__ short As[64 * LDSW];
  __shared__ short Bs[64 * LDSW];
  const int tid = threadIdx.x;
  const int lane = tid & 63, w = tid >> 6;
  const int wr = w >> 1, wc = w & 1;
  const int m0 = blockIdx.y << 6, n0 = blockIdx.x << 6;
  // staging coords
  const int ar = tid >> 2, ac = (tid & 3) << 3;   // A: row ar (0..63), k ac..ac+7
  const int bk = tid >> 3, bn = (tid & 7) << 3;   // W: k bk (0..31), n bn..bn+7
  const int aswz = (((ac >> 3) ^ (ar >> 3)) & 3) << 3;
  const int l15 = lane & 15, lc = lane >> 4;
  f32x4 acc[2][2] = {};
  for (int kt = 0; kt < K; kt += 32) {
    float4 a0 = make_float4(0.f, 0.f, 0.f, 0.f), a1 = a0;
    if (m0 + ar < M) {
      const float* ap = A + (size_t)(m0 + ar) * K + kt + ac;
      a0 = ((const float4*)ap)[0]; a1 = ((const float4*)ap)[1];
    }
    const float* wp = W + (size_t)(kt + bk) * Nn + n0 + bn;
    const float4 b0 = ((const float4*)wp)[0], b1 = ((const float4*)wp)[1];
    __syncthreads();   // previous tile fully consumed
    {
      bf16x8 av;
      av[0] = (short)f2bf(a0.x); av[1] = (short)f2bf(a0.y);
      av[2] = (short)f2bf(a0.z); av[3] = (short)f2bf(a0.w);
      av[4] = (short)f2bf(a1.x); av[5] = (short)f2bf(a1.y);
      av[6] = (short)f2bf(a1.z); av[7] = (short)f2bf(a1.w);
      *(bf16x8*)&As[ar * LDSW + aswz] = av;
      unsigned short bb[8] = {f2bf(b0.x), f2bf(b0.y), f2bf(b0.z), f2bf(b0.w),
                              f2bf(b1.x), f2bf(b1.y), f2bf(b1.z), f2bf(b1.w)};
      const int bchunk = bk >> 3, bke = bk & 7;
#pragma unroll
      for (int j = 0; j < 8; j++) {
        const int n = bn + j;
        Bs[n * LDSW + (((bchunk ^ (n >> 3)) & 3) << 3) + bke] = (short)bb[j];
      }
    }
    __syncthreads();
    bf16x8 af[2], bf[2];
#pragma unroll
    for (int i = 0; i < 2; i++) {
      const int row = wr * 32 + i * 16 + l15;
      af[i] = *(const bf16x8*)&As[row * LDSW + (((lc ^ (row >> 3)) & 3) << 3)];
      const int col = wc * 32 + i * 16 + l15;
      bf[i] = *(const bf16x8*)&Bs[col * LDSW + (((lc ^ (col >> 3)) & 3) << 3)];
    }
#pragma unroll
    for (int i = 0; i < 2; i++)
#pragma unroll
      for (int j = 0; j < 2; j++)
        acc[i][j] = __builtin_amdgcn_mfma_f32_16x16x32_bf16(af[i], bf[j], acc[i][j], 0, 0, 0);
  }
  // epilogue: D layout col = lane&15, row = (lane>>4)*4 + reg
#pragma unroll
  for (int i = 0; i < 2; i++) {
    const int row0 = m0 + wr * 32 + i * 16 + lc * 4;
#pragma unroll
    for (int j = 0; j < 2; j++) {
      const int col = n0 + wc * 32 + j * 16 + l15;
      const float bv = bias[col];
#pragma unroll
      for (int r = 0; r < 4; r++) {
        const int row = row0 + r;
        if (row < M) {
          float v = (acc[i][j][r] + bv) * scale;
          if (relu) v = fmaxf(v, 0.f);
          C[(size_t)row * Nn + col] = v;
        }
      }
    }
  }
}

// ---------------- exact flash attention, 4 sub-lanes per query ----------------
// Q,K,V,O: (N, LQ, 256), head h at channels h*32..h*32+31. Q pre-scaled.
// Block: 256 threads = 64 queries x 4 sub-lanes; each sub handles keys j%4==sub.
__global__ __launch_bounds__(256) void attn_kernel(const float* __restrict__ Qg,
                                                   const float* __restrict__ Kg,
                                                   const float* __restrict__ Vg,
                                                   float* __restrict__ O) {
  __shared__ float Ks[64][36];
  __shared__ float Vs[64][36];
  const int tid = threadIdx.x;
  const int h = blockIdx.y, b = blockIdx.z;
  const int sub = tid & 3, qi = tid >> 2;
  const int q = blockIdx.x * 64 + qi;
  const bool qv = q < LQ;
  float qreg[32];
  {
    const float* qp = Qg + ((size_t)(b * LQ + (qv ? q : 0))) * DM + h * DH;
#pragma unroll
    for (int c = 0; c < 32; c += 4) {
      float4 v = *(const float4*)(qp + c);
      qreg[c] = v.x; qreg[c + 1] = v.y; qreg[c + 2] = v.z; qreg[c + 3] = v.w;
    }
  }
  float o[32];
#pragma unroll
  for (int c = 0; c < 32; c++) o[c] = 0.f;
  float m = -INFINITY, lsum = 0.f;
  const int r = tid >> 2, c0 = (tid & 3) << 3;  // staging: 1 row x 8 cols each
  for (int kt = 0; kt < LQ; kt += 64) {
    const int kr = kt + r;
    const bool rv = kr < LQ;
    const float* kp = Kg + ((size_t)(b * LQ + (rv ? kr : 0))) * DM + h * DH + c0;
    const float* vp = Vg + ((size_t)(b * LQ + (rv ? kr : 0))) * DM + h * DH + c0;
    float4 k0 = make_float4(0, 0, 0, 0), k1 = k0, v0 = k0, v1 = k0;
    if (rv) {
      k0 = ((const float4*)kp)[0]; k1 = ((const float4*)kp)[1];
      v0 = ((const float4*)vp)[0]; v1 = ((const float4*)vp)[1];
    }
    __syncthreads();
    *(float4*)&Ks[r][c0] = k0; *(float4*)&Ks[r][c0 + 4] = k1;
    *(float4*)&Vs[r][c0] = v0; *(float4*)&Vs[r][c0 + 4] = v1;
    __syncthreads();
    const int kn = min(64, LQ - kt);
    float s[16];
#pragma unroll
    for (int jj = 0; jj < 16; jj++) {
      const int j = (jj << 2) | sub;
      float a = 0.f;
#pragma unroll
      for (int c = 0; c < 32; c++) a += qreg[c] * Ks[j][c];
      s[jj] = (j < kn) ? a : -INFINITY;
    }
    float tm = m;
#pragma unroll
    for (int jj = 0; jj < 16; jj++) tm = fmaxf(tm, s[jj]);
    const float f = __expf(m - tm);
    lsum *= f;
#pragma unroll
    for (int c = 0; c < 32; c++) o[c] *= f;
#pragma unroll
    for (int jj = 0; jj < 16; jj++) {
      const float p = __expf(s[jj] - tm);
      lsum += p;
      const int j = (jj << 2) | sub;
#pragma unroll
      for (int c = 0; c < 32; c++) o[c] += p * Vs[j][c];
    }
    m = tm;
  }
  // combine 4 sub-lane partials (consecutive lanes) via butterfly
  float M2 = fmaxf(m, __shfl_xor(m, 1));
  M2 = fmaxf(M2, __shfl_xor(M2, 2));
  const float f = __expf(m - M2);
  lsum *= f;
  lsum += __shfl_xor(lsum, 1);
  lsum += __shfl_xor(lsum, 2);
#pragma unroll
  for (int c = 0; c < 32; c++) {
    o[c] *= f;
    o[c] += __shfl_xor(o[c], 1);
    o[c] += __shfl_xor(o[c], 2);
  }
  if (qv) {
    const float inv = 1.f / lsum;
    float out8[8];
#pragma unroll
    for (int c = 0; c < 8; c++) {
      const float v = (sub == 0) ? o[c] : (sub == 1) ? o[8 + c]
                    : (sub == 2) ? o[16 + c] : o[24 + c];
      out8[c] = v * inv;
    }
    float* op = O + ((size_t)(b * LQ + q)) * DM + h * DH + (sub << 3);
    *(float4*)op = make_float4(out8[0], out8[1], out8[2], out8[3]);
    *(float4*)(op + 4) = make_float4(out8[4], out8[5], out8[6], out8[7]);
  }
}

// ---------------- softmax over 16 deform attn weights per (b,q,h) ----------------
__global__ __launch_bounds__(256) void softmax16_kernel(float* __restrict__ att, int n) {
  int t = blockIdx.x * 256 + threadIdx.x;
  if (t >= n) return;
  float* p = att + (size_t)t * 16;
  float v[16];
#pragma unroll
  for (int i = 0; i < 16; i++) v[i] = p[i];
  float m = v[0];
#pragma unroll
  for (int i = 1; i < 16; i++) m = fmaxf(m, v[i]);
  float s = 0.f;
#pragma unroll
  for (int i = 0; i < 16; i++) { v[i] = __expf(v[i] - m); s += v[i]; }
  const float inv = 1.f / s;
#pragma unroll
  for (int i = 0; i < 16; i++) p[i] = v[i] * inv;
}

// ---------------- MS-deform bilinear sampling ----------------
__global__ __launch_bounds__(256) void sample_kernel(const float* __restrict__ value,
                                                     const float* __restrict__ ref,
                                                     const float* __restrict__ off,
                                                     const float* __restrict__ att,
                                                     float* __restrict__ out) {
  const int t = blockIdx.x * 256 + threadIdx.x;  // < NB*LQ*256
  const int d = t & 31;
  const int h = (t >> 5) & 7;
  const int q = (t >> 8) % LQ;
  const int b = t / (LQ * 256);
  const int HLs[4] = {100, 50, 25, 13};
  const int WLs[4] = {100, 50, 25, 13};
  const int STs[4] = {0, 10000, 12500, 13125};
  const float* rp = ref + ((size_t)(b * LQ + q)) * (NL * 2);
  const float* op = off + ((size_t)(b * LQ + q)) * DM + h * (NL * NP * 2);
  const float* ap = att + ((size_t)(b * LQ + q)) * (NH * NL * NP) + h * (NL * NP);
  const float* vb = value + (size_t)b * LIN * DM + h * DH + d;
  float acc = 0.f;
#pragma unroll
  for (int l = 0; l < NL; l++) {
    const int Hl = HLs[l], Wl = WLs[l], st = STs[l];
    const float rx = rp[l * 2], ry = rp[l * 2 + 1];
#pragma unroll
    for (int p = 0; p < NP; p++) {
      const float ox = op[(l * NP + p) * 2], oy = op[(l * NP + p) * 2 + 1];
      const float a = ap[l * NP + p];
      const float locx = rx + ox / (float)Wl;
      const float locy = ry + oy / (float)Hl;
      const float x = locx * (float)Wl - 0.5f;
      const float y = locy * (float)Hl - 0.5f;
      const float xf = floorf(x), yf = floorf(y);
      const float fx = x - xf, fy = y - yf;
      const int x0 = (int)xf, y0 = (int)yf;
      float g00 = 0.f, g10 = 0.f, g01 = 0.f, g11 = 0.f;
      if (y0 >= 0 && y0 < Hl) {
        const float* rowp = vb + (size_t)(st + y0 * Wl) * DM;
        if (x0 >= 0 && x0 < Wl) g00 = rowp[(size_t)x0 * DM];
        if (x0 + 1 >= 0 && x0 + 1 < Wl) g10 = rowp[(size_t)(x0 + 1) * DM];
      }
      if (y0 + 1 >= 0 && y0 + 1 < Hl) {
        const float* rowp = vb + (size_t)(st + (y0 + 1) * Wl) * DM;
        if (x0 >= 0 && x0 < Wl) g01 = rowp[(size_t)x0 * DM];
        if (x0 + 1 >= 0 && x0 + 1 < Wl) g11 = rowp[(size_t)(x0 + 1) * DM];
      }
      acc += a * ((1.f - fx) * (1.f - fy) * g00 + fx * (1.f - fy) * g10 +
                  (1.f - fx) * fy * g01 + fx * fy * g11);
    }
  }
  out[t] = acc;
}

// ---------------- fused residual-add + LayerNorm, wave per row ----------------
__global__ __launch_bounds__(64) void ln_kernel(const float* __restrict__ A,
                                                const float* __restrict__ R,
                                                const float* __restrict__ g,
                                                const float* __restrict__ be,
                                                float* __restrict__ out) {
  const int row = blockIdx.x, t = threadIdx.x;
  const float4 va = ((const float4*)(A + (size_t)row * DM))[t];
  const float4 vr = ((const float4*)(R + (size_t)row * DM))[t];
  const float x0 = va.x + vr.x, x1 = va.y + vr.y, x2 = va.z + vr.z, x3 = va.w + vr.w;
  float s = x0 + x1 + x2 + x3;
  float ss = x0 * x0 + x1 * x1 + x2 * x2 + x3 * x3;
#pragma unroll
  for (int o = 1; o < 64; o <<= 1) { s += __shfl_xor(s, o); ss += __shfl_xor(ss, o); }
  const float mean = s * (1.f / DM);
  const float var = ss * (1.f / DM) - mean * mean;
  const float rstd = rsqrtf(var + 1e-5f);
  const float4 vg = ((const float4*)g)[t];
  const float4 vb = ((const float4*)be)[t];
  float4 o4;
  o4.x = (x0 - mean) * rstd * vg.x + vb.x;
  o4.y = (x1 - mean) * rstd * vg.y + vb.y;
  o4.z = (x2 - mean) * rstd * vg.z + vb.z;
  o4.w = (x3 - mean) * rstd * vg.w + vb.w;
  ((float4*)(out + (size_t)row * DM))[t] = o4;
}

extern "C" void kernel_launch(void* const* d_in, const int* in_sizes, int n_in,
                              void* d_out, int out_size, void* d_ws, size_t ws_size,
                              hipStream_t stream) {
  const float* tgt  = (const float*)d_in[1];
  const float* qpos = (const float*)d_in[2];
  const float* ref  = (const float*)d_in[3];
  const float* src  = (const float*)d_in[4];
  const float* wq = (const float*)d_in[8];  const float* bq = (const float*)d_in[9];
  const float* wk = (const float*)d_in[10]; const float* bk = (const float*)d_in[11];
  const float* wv = (const float*)d_in[12]; const float* bv = (const float*)d_in[13];
  const float* wo = (const float*)d_in[14]; const float* bo = (const float*)d_in[15];
  const float* w_val = (const float*)d_in[16]; const float* b_val = (const float*)d_in[17];
  const float* w_off = (const float*)d_in[18]; const float* b_off = (const float*)d_in[19];
  const float* w_att = (const float*)d_in[20]; const float* b_att = (const float*)d_in[21];
  const float* w_out = (const float*)d_in[22]; const float* b_out = (const float*)d_in[23];
  const float* ln1g = (const float*)d_in[24]; const float* ln1b = (const float*)d_in[25];
  const float* ln2g = (const float*)d_in[26]; const float* ln2b = (const float*)d_in[27];
  const float* ln3g = (const float*)d_in[28]; const float* ln3b = (const float*)d_in[29];
  const float* w1 = (const float*)d_in[30]; const float* b1 = (const float*)d_in[31];
  const float* w2 = (const float*)d_in[32]; const float* b2 = (const float*)d_in[33];

  const size_t S = (size_t)MROW * DM;
  const size_t VAL_F = (size_t)NVAL * DM;
  float* ws = (float*)d_ws;
  float* value = ws;
  float* B0   = ws + VAL_F;
  float* qin  = B0 + 0 * S;
  float* Qb   = B0 + 1 * S;
  float* Kb   = B0 + 2 * S;
  float* Vb   = B0 + 3 * S;
  float* Ob   = B0 + 4 * S;
  float* tmp  = B0 + 5 * S;
  float* x1   = B0 + 0 * S;
  float* q2   = B0 + 1 * S;
  float* offb = B0 + 2 * S;
  float* attb = B0 + 3 * S;
  float* samp = B0 + 4 * S;
  float* x2   = B0 + 6 * S;
  float* hffn = B0 + 1 * S;

  const float qscale = 0.17677669529663687f;  // 1/sqrt(32)
  const int n4 = (int)(S / 4);
  const dim3 blk(256);
  const dim3 gAdd((n4 + 255) / 256);
  const dim3 gQ(DM / 64, (MROW + 63) / 64);       // (4,113)
  const dim3 gAtt(2, (MROW + 63) / 64);           // N=128
  const dim3 gVal(DM / 64, (NVAL + 63) / 64);     // (4,1662)
  const dim3 gF1(DFFN / 64, (MROW + 63) / 64);    // (16,113)

  // ---- self-attention ----
  add_kernel<<<gAdd, blk, 0, stream>>>(tgt, qpos, qin, n4);
  gemm_bf16<<<gQ, blk, 0, stream>>>(qin, wq, bq, Qb, MROW, DM, DM, qscale, 0);
  gemm_bf16<<<gQ, blk, 0, stream>>>(qin, wk, bk, Kb, MROW, DM, DM, 1.f, 0);
  gemm_bf16<<<gQ, blk, 0, stream>>>(tgt, wv, bv, Vb, MROW, DM, DM, 1.f, 0);
  attn_kernel<<<dim3((LQ + 63) / 64, NH, NB), blk, 0, stream>>>(Qb, Kb, Vb, Ob);
  gemm_bf16<<<gQ, blk, 0, stream>>>(Ob, wo, bo, tmp, MROW, DM, DM, 1.f, 0);
  ln_kernel<<<dim3(MROW), dim3(64), 0, stream>>>(tmp, tgt, ln2g, ln2b, x1);

  // ---- deformable cross-attention ----
  gemm_bf16<<<gVal, blk, 0, stream>>>(src, w_val, b_val, value, NVAL, DM, DM, 1.f, 0);
  add_kernel<<<gAdd, blk, 0, stream>>>(x1, qpos, q2, n4);
  gemm_bf16<<<gQ, blk, 0, stream>>>(q2, w_off, b_off, offb, MROW, DM, DM, 1.f, 0);
  gemm_bf16<<<gAtt, blk, 0, stream>>>(q2, w_att, b_att, attb, MROW, NH * NL * NP, DM, 1.f, 0);
  softmax16_kernel<<<dim3((MROW * NH + 255) / 256), blk, 0, stream>>>(attb, MROW * NH);
  sample_kernel<<<dim3(MROW), blk, 0, stream>>>(value, ref, offb, attb, samp);
  gemm_bf16<<<gQ, blk, 0, stream>>>(samp, w_out, b_out, tmp, MROW, DM, DM, 1.f, 0);
  ln_kernel<<<dim3(MROW), dim3(64), 0, stream>>>(tmp, x1, ln1g, ln1b, x2);

  // ---- FFN ----
  gemm_bf16<<<gF1, blk, 0, stream>>>(x2, w1, b1, hffn, MROW, DFFN, DM, 1.f, 1);
  gemm_bf16<<<gQ, blk, 0, stream>>>(hffn, w2, b2, tmp, MROW, DM, DFFN, 1.f, 0);
  ln_kernel<<<dim3(MROW), dim3(64), 0, stream>>>(tmp, x2, ln3g, ln3b, (float*)d_out);
}

// Round 3
// 450.297 us; speedup vs baseline: 2.0142x; 1.2573x over previous
//
#include <hip/hip_runtime.h>
#include <math.h>

#define NB 8
#define LQ 900
#define DM 256
#define NH 8
#define DH 32
#define NL 4
#define NP 4
#define DFFN 1024
#define LIN 13294
#define NVAL (NB*LIN)      // 106352 rows for value projection
#define MROW (NB*LQ)       // 7200 rows for query-side matmuls

typedef __attribute__((ext_vector_type(8))) short bf16x8;
typedef __attribute__((ext_vector_type(4))) float f32x4;

__device__ __forceinline__ unsigned short f2bf(float x) {
  unsigned u = __float_as_uint(x);
  u += 0x7FFFu + ((u >> 16) & 1u);   // round-to-nearest-even
  return (unsigned short)(u >> 16);
}

// ---------------- elementwise add (float4) ----------------
__global__ __launch_bounds__(256) void add_kernel(const float* __restrict__ a,
                                                  const float* __restrict__ b,
                                                  float* __restrict__ c, int n4) {
  int i = blockIdx.x * 256 + threadIdx.x;
  if (i < n4) {
    float4 x = ((const float4*)a)[i];
    float4 y = ((const float4*)b)[i];
    ((float4*)c)[i] = make_float4(x.x + y.x, x.y + y.y, x.z + y.z, x.w + y.w);
  }
}

// ---------------- bf16 MFMA GEMM: C = (A@W + bias)*scale, opt relu ----------------
#define LDSW 40   // LDS row stride in bf16 elems
__global__ __launch_bounds__(256) void gemm_bf16(const float* __restrict__ A,
                                                 const float* __restrict__ W,
                                                 const float* __restrict__ bias,
                                                 float* __restrict__ C,
                                                 int M, int Nn, int K, float scale, int relu) {
  __shared__ short As[64 * LDSW];
  __shared__ short Bs[64 * LDSW];
  const int tid = threadIdx.x;
  const int lane = tid & 63, w = tid >> 6;
  const int wr = w >> 1, wc = w & 1;
  const int m0 = blockIdx.y << 6, n0 = blockIdx.x << 6;
  const int ar = tid >> 2, ac = (tid & 3) << 3;
  const int bk = tid >> 3, bn = (tid & 7) << 3;
  const int aswz = (((ac >> 3) ^ (ar >> 3)) & 3) << 3;
  const int l15 = lane & 15, lc = lane >> 4;
  f32x4 acc[2][2] = {};
  for (int kt = 0; kt < K; kt += 32) {
    float4 a0 = make_float4(0.f, 0.f, 0.f, 0.f), a1 = a0;
    if (m0 + ar < M) {
      const float* ap = A + (size_t)(m0 + ar) * K + kt + ac;
      a0 = ((const float4*)ap)[0]; a1 = ((const float4*)ap)[1];
    }
    const float* wp = W + (size_t)(kt + bk) * Nn + n0 + bn;
    const float4 b0 = ((const float4*)wp)[0], b1 = ((const float4*)wp)[1];
    __syncthreads();
    {
      bf16x8 av;
      av[0] = (short)f2bf(a0.x); av[1] = (short)f2bf(a0.y);
      av[2] = (short)f2bf(a0.z); av[3] = (short)f2bf(a0.w);
      av[4] = (short)f2bf(a1.x); av[5] = (short)f2bf(a1.y);
      av[6] = (short)f2bf(a1.z); av[7] = (short)f2bf(a1.w);
      *(bf16x8*)&As[ar * LDSW + aswz] = av;
      unsigned short bb[8] = {f2bf(b0.x), f2bf(b0.y), f2bf(b0.z), f2bf(b0.w),
                              f2bf(b1.x), f2bf(b1.y), f2bf(b1.z), f2bf(b1.w)};
      const int bchunk = bk >> 3, bke = bk & 7;
#pragma unroll
      for (int j = 0; j < 8; j++) {
        const int n = bn + j;
        Bs[n * LDSW + (((bchunk ^ (n >> 3)) & 3) << 3) + bke] = (short)bb[j];
      }
    }
    __syncthreads();
    bf16x8 af[2], bf[2];
#pragma unroll
    for (int i = 0; i < 2; i++) {
      const int row = wr * 32 + i * 16 + l15;
      af[i] = *(const bf16x8*)&As[row * LDSW + (((lc ^ (row >> 3)) & 3) << 3)];
      const int col = wc * 32 + i * 16 + l15;
      bf[i] = *(const bf16x8*)&Bs[col * LDSW + (((lc ^ (col >> 3)) & 3) << 3)];
    }
#pragma unroll
    for (int i = 0; i < 2; i++)
#pragma unroll
      for (int j = 0; j < 2; j++)
        acc[i][j] = __builtin_amdgcn_mfma_f32_16x16x32_bf16(af[i], bf[j], acc[i][j], 0, 0, 0);
  }
#pragma unroll
  for (int i = 0; i < 2; i++) {
    const int row0 = m0 + wr * 32 + i * 16 + lc * 4;
#pragma unroll
    for (int j = 0; j < 2; j++) {
      const int col = n0 + wc * 32 + j * 16 + l15;
      const float bv = bias[col];
#pragma unroll
      for (int r = 0; r < 4; r++) {
        const int row = row0 + r;
        if (row < M) {
          float v = (acc[i][j][r] + bv) * scale;
          if (relu) v = fmaxf(v, 0.f);
          C[(size_t)row * Nn + col] = v;
        }
      }
    }
  }
}

// ---------------- MFMA flash attention ----------------
// Block: 256 thr = 4 waves; 64 queries per block (16/wave), one (b,h).
// Q pre-scaled. K tile 64 x 32 in LDS (swizzled); V^T 32 x 64 (quad-swizzled);
// P per-wave 16x64 bf16 strip (row-swizzled).
__global__ __launch_bounds__(256) void attn_mfma(const float* __restrict__ Qg,
                                                 const float* __restrict__ Kg,
                                                 const float* __restrict__ Vg,
                                                 float* __restrict__ O) {
  __shared__ short Ks[2048];   // 4 KB
  __shared__ short Vt[2048];   // 4 KB
  __shared__ short Pl[4096];   // 8 KB (4 waves x 2 KB)
  const int tid = threadIdx.x;
  const int lane = tid & 63, w = tid >> 6;
  const int l15 = lane & 15, lc = lane >> 4;
  const int h = blockIdx.y, b = blockIdx.z;
  const int q0 = blockIdx.x * 64;
  char* KsB = (char*)Ks; char* VtB = (char*)Vt; char* PlB = (char*)Pl + w * 2048;

  bf16x8 qa;
  {
    const int qrow = min(q0 + w * 16 + l15, LQ - 1);
    const float* qp = Qg + ((size_t)(b * LQ + qrow)) * DM + h * DH + lc * 8;
    const float4 qx = ((const float4*)qp)[0], qy = ((const float4*)qp)[1];
    qa[0] = (short)f2bf(qx.x); qa[1] = (short)f2bf(qx.y);
    qa[2] = (short)f2bf(qx.z); qa[3] = (short)f2bf(qx.w);
    qa[4] = (short)f2bf(qy.x); qa[5] = (short)f2bf(qy.y);
    qa[6] = (short)f2bf(qy.z); qa[7] = (short)f2bf(qy.w);
  }
  f32x4 o0 = {0.f, 0.f, 0.f, 0.f}, o1 = {0.f, 0.f, 0.f, 0.f};
  float mrow[4], lrow[4];
#pragma unroll
  for (int r = 0; r < 4; r++) { mrow[r] = -1e30f; lrow[r] = 0.f; }
  const int skey = tid >> 2, sq = tid & 3;

  for (int kt = 0; kt < LQ; kt += 64) {
    const int kr = min(kt + skey, LQ - 1);
    const float* kp = Kg + ((size_t)(b * LQ + kr)) * DM + h * DH + sq * 8;
    const float* vp = Vg + ((size_t)(b * LQ + kr)) * DM + h * DH + sq * 8;
    const float4 k0 = ((const float4*)kp)[0], k1 = ((const float4*)kp)[1];
    const float4 v0 = ((const float4*)vp)[0], v1 = ((const float4*)vp)[1];
    __syncthreads();   // prev tile's LDS reads done
    {
      bf16x8 kb;
      kb[0] = (short)f2bf(k0.x); kb[1] = (short)f2bf(k0.y);
      kb[2] = (short)f2bf(k0.z); kb[3] = (short)f2bf(k0.w);
      kb[4] = (short)f2bf(k1.x); kb[5] = (short)f2bf(k1.y);
      kb[6] = (short)f2bf(k1.z); kb[7] = (short)f2bf(k1.w);
      *(bf16x8*)(KsB + ((skey * 64 + sq * 16) ^ ((skey & 7) << 4))) = kb;
      unsigned short vv[8] = {f2bf(v0.x), f2bf(v0.y), f2bf(v0.z), f2bf(v0.w),
                              f2bf(v1.x), f2bf(v1.y), f2bf(v1.z), f2bf(v1.w)};
#pragma unroll
      for (int j = 0; j < 8; j++) {
        const int dh = sq * 8 + j;
        const int qz = ((dh & 7) ^ (((dh >> 3) & 3) << 1)) << 4;
        *(short*)(VtB + ((dh * 128 + skey * 2) ^ qz)) = (short)vv[j];
      }
    }
    __syncthreads();   // staging visible
    // ---- S = Q @ K^T ----
    f32x4 s[4];
#pragma unroll
    for (int cb = 0; cb < 4; cb++) {
      const int key = cb * 16 + l15;
      const bf16x8 kf = *(const bf16x8*)(KsB + ((key * 64 + lc * 16) ^ ((key & 7) << 4)));
      const f32x4 z = {0.f, 0.f, 0.f, 0.f};
      s[cb] = __builtin_amdgcn_mfma_f32_16x16x32_bf16(qa, kf, z, 0, 0, 0);
    }
#pragma unroll
    for (int cb = 0; cb < 4; cb++)
      if (kt + cb * 16 + l15 >= LQ) {
        s[cb][0] = -1e30f; s[cb][1] = -1e30f; s[cb][2] = -1e30f; s[cb][3] = -1e30f;
      }
    // ---- online softmax (rows = lc*4 + r) ----
    float tm[4], fs[4], ps[4];
#pragma unroll
    for (int r = 0; r < 4; r++)
      tm[r] = fmaxf(fmaxf(s[0][r], s[1][r]), fmaxf(s[2][r], s[3][r]));
#pragma unroll
    for (int msk = 1; msk <= 8; msk <<= 1)
#pragma unroll
      for (int r = 0; r < 4; r++) tm[r] = fmaxf(tm[r], __shfl_xor(tm[r], msk));
#pragma unroll
    for (int r = 0; r < 4; r++) {
      const float nm = fmaxf(mrow[r], tm[r]);
      fs[r] = __expf(mrow[r] - nm);
      mrow[r] = nm;
    }
#pragma unroll
    for (int cb = 0; cb < 4; cb++)
#pragma unroll
      for (int r = 0; r < 4; r++) s[cb][r] = __expf(s[cb][r] - mrow[r]);
#pragma unroll
    for (int r = 0; r < 4; r++) ps[r] = (s[0][r] + s[1][r]) + (s[2][r] + s[3][r]);
#pragma unroll
    for (int msk = 1; msk <= 8; msk <<= 1)
#pragma unroll
      for (int r = 0; r < 4; r++) ps[r] += __shfl_xor(ps[r], msk);
#pragma unroll
    for (int r = 0; r < 4; r++) {
      lrow[r] = lrow[r] * fs[r] + ps[r];
      o0[r] *= fs[r]; o1[r] *= fs[r];
    }
    // ---- P -> LDS (bf16, own-wave strip) ----
#pragma unroll
    for (int cb = 0; cb < 4; cb++)
#pragma unroll
      for (int r = 0; r < 4; r++) {
        const int row = lc * 4 + r, col = cb * 16 + l15;
        *(short*)(PlB + ((row * 128 + col * 2) ^ ((row & 7) << 4))) = (short)f2bf(s[cb][r]);
      }
    // ---- O += P @ V ----
#pragma unroll
    for (int ks2 = 0; ks2 < 2; ks2++) {
      const int koff2 = (ks2 * 32 + lc * 8) * 2;
      const bf16x8 pa = *(const bf16x8*)(PlB + ((l15 * 128 + koff2) ^ ((l15 & 7) << 4)));
      {
        const int dh = l15;
        const int qz = ((dh & 7) ^ (((dh >> 3) & 3) << 1)) << 4;
        const bf16x8 vf = *(const bf16x8*)(VtB + ((dh * 128 + koff2) ^ qz));
        o0 = __builtin_amdgcn_mfma_f32_16x16x32_bf16(pa, vf, o0, 0, 0, 0);
      }
      {
        const int dh = 16 + l15;
        const int qz = ((dh & 7) ^ (((dh >> 3) & 3) << 1)) << 4;
        const bf16x8 vf = *(const bf16x8*)(VtB + ((dh * 128 + koff2) ^ qz));
        o1 = __builtin_amdgcn_mfma_f32_16x16x32_bf16(pa, vf, o1, 0, 0, 0);
      }
    }
  }
#pragma unroll
  for (int r = 0; r < 4; r++) {
    const int qrow = q0 + w * 16 + lc * 4 + r;
    if (qrow < LQ) {
      const float inv = 1.f / lrow[r];
      float* op = O + ((size_t)(b * LQ + qrow)) * DM + h * DH;
      op[l15] = o0[r] * inv;
      op[16 + l15] = o1[r] * inv;
    }
  }
}

// ---------------- softmax over 16 deform attn weights per (b,q,h) ----------------
__global__ __launch_bounds__(256) void softmax16_kernel(float* __restrict__ att, int n) {
  int t = blockIdx.x * 256 + threadIdx.x;
  if (t >= n) return;
  float* p = att + (size_t)t * 16;
  float v[16];
#pragma unroll
  for (int i = 0; i < 16; i++) v[i] = p[i];
  float m = v[0];
#pragma unroll
  for (int i = 1; i < 16; i++) m = fmaxf(m, v[i]);
  float s = 0.f;
#pragma unroll
  for (int i = 0; i < 16; i++) { v[i] = __expf(v[i] - m); s += v[i]; }
  const float inv = 1.f / s;
#pragma unroll
  for (int i = 0; i < 16; i++) p[i] = v[i] * inv;
}

// ---------------- MS-deform bilinear sampling ----------------
__global__ __launch_bounds__(256) void sample_kernel(const float* __restrict__ value,
                                                     const float* __restrict__ ref,
                                                     const float* __restrict__ off,
                                                     const float* __restrict__ att,
                                                     float* __restrict__ out) {
  const int t = blockIdx.x * 256 + threadIdx.x;
  const int d = t & 31;
  const int h = (t >> 5) & 7;
  const int q = (t >> 8) % LQ;
  const int b = t / (LQ * 256);
  const int HLs[4] = {100, 50, 25, 13};
  const int WLs[4] = {100, 50, 25, 13};
  const int STs[4] = {0, 10000, 12500, 13125};
  const float* rp = ref + ((size_t)(b * LQ + q)) * (NL * 2);
  const float* op = off + ((size_t)(b * LQ + q)) * DM + h * (NL * NP * 2);
  const float* ap = att + ((size_t)(b * LQ + q)) * (NH * NL * NP) + h * (NL * NP);
  const float* vb = value + (size_t)b * LIN * DM + h * DH + d;
  float acc = 0.f;
#pragma unroll
  for (int l = 0; l < NL; l++) {
    const int Hl = HLs[l], Wl = WLs[l], st = STs[l];
    const float rx = rp[l * 2], ry = rp[l * 2 + 1];
#pragma unroll
    for (int p = 0; p < NP; p++) {
      const float ox = op[(l * NP + p) * 2], oy = op[(l * NP + p) * 2 + 1];
      const float a = ap[l * NP + p];
      const float locx = rx + ox / (float)Wl;
      const float locy = ry + oy / (float)Hl;
      const float x = locx * (float)Wl - 0.5f;
      const float y = locy * (float)Hl - 0.5f;
      const float xf = floorf(x), yf = floorf(y);
      const float fx = x - xf, fy = y - yf;
      const int x0 = (int)xf, y0 = (int)yf;
      float g00 = 0.f, g10 = 0.f, g01 = 0.f, g11 = 0.f;
      if (y0 >= 0 && y0 < Hl) {
        const float* rowp = vb + (size_t)(st + y0 * Wl) * DM;
        if (x0 >= 0 && x0 < Wl) g00 = rowp[(size_t)x0 * DM];
        if (x0 + 1 >= 0 && x0 + 1 < Wl) g10 = rowp[(size_t)(x0 + 1) * DM];
      }
      if (y0 + 1 >= 0 && y0 + 1 < Hl) {
        const float* rowp = vb + (size_t)(st + (y0 + 1) * Wl) * DM;
        if (x0 >= 0 && x0 < Wl) g01 = rowp[(size_t)x0 * DM];
        if (x0 + 1 >= 0 && x0 + 1 < Wl) g11 = rowp[(size_t)(x0 + 1) * DM];
      }
      acc += a * ((1.f - fx) * (1.f - fy) * g00 + fx * (1.f - fy) * g10 +
                  (1.f - fx) * fy * g01 + fx * fy * g11);
    }
  }
  out[t] = acc;
}

// ---------------- fused residual-add + LayerNorm, wave per row ----------------
__global__ __launch_bounds__(64) void ln_kernel(const float* __restrict__ A,
                                                const float* __restrict__ R,
                                                const float* __restrict__ g,
                                                const float* __restrict__ be,
                                                float* __restrict__ out) {
  const int row = blockIdx.x, t = threadIdx.x;
  const float4 va = ((const float4*)(A + (size_t)row * DM))[t];
  const float4 vr = ((const float4*)(R + (size_t)row * DM))[t];
  const float x0 = va.x + vr.x, x1 = va.y + vr.y, x2 = va.z + vr.z, x3 = va.w + vr.w;
  float s = x0 + x1 + x2 + x3;
  float ss = x0 * x0 + x1 * x1 + x2 * x2 + x3 * x3;
#pragma unroll
  for (int o = 1; o < 64; o <<= 1) { s += __shfl_xor(s, o); ss += __shfl_xor(ss, o); }
  const float mean = s * (1.f / DM);
  const float var = ss * (1.f / DM) - mean * mean;
  const float rstd = rsqrtf(var + 1e-5f);
  const float4 vg = ((const float4*)g)[t];
  const float4 vb = ((const float4*)be)[t];
  float4 o4;
  o4.x = (x0 - mean) * rstd * vg.x + vb.x;
  o4.y = (x1 - mean) * rstd * vg.y + vb.y;
  o4.z = (x2 - mean) * rstd * vg.z + vb.z;
  o4.w = (x3 - mean) * rstd * vg.w + vb.w;
  ((float4*)(out + (size_t)row * DM))[t] = o4;
}

extern "C" void kernel_launch(void* const* d_in, const int* in_sizes, int n_in,
                              void* d_out, int out_size, void* d_ws, size_t ws_size,
                              hipStream_t stream) {
  const float* tgt  = (const float*)d_in[1];
  const float* qpos = (const float*)d_in[2];
  const float* ref  = (const float*)d_in[3];
  const float* src  = (const float*)d_in[4];
  const float* wq = (const float*)d_in[8];  const float* bq = (const float*)d_in[9];
  const float* wk = (const float*)d_in[10]; const float* bk = (const float*)d_in[11];
  const float* wv = (const float*)d_in[12]; const float* bv = (const float*)d_in[13];
  const float* wo = (const float*)d_in[14]; const float* bo = (const float*)d_in[15];
  const float* w_val = (const float*)d_in[16]; const float* b_val = (const float*)d_in[17];
  const float* w_off = (const float*)d_in[18]; const float* b_off = (const float*)d_in[19];
  const float* w_att = (const float*)d_in[20]; const float* b_att = (const float*)d_in[21];
  const float* w_out = (const float*)d_in[22]; const float* b_out = (const float*)d_in[23];
  const float* ln1g = (const float*)d_in[24]; const float* ln1b = (const float*)d_in[25];
  const float* ln2g = (const float*)d_in[26]; const float* ln2b = (const float*)d_in[27];
  const float* ln3g = (const float*)d_in[28]; const float* ln3b = (const float*)d_in[29];
  const float* w1 = (const float*)d_in[30]; const float* b1 = (const float*)d_in[31];
  const float* w2 = (const float*)d_in[32]; const float* b2 = (const float*)d_in[33];

  const size_t S = (size_t)MROW * DM;
  const size_t VAL_F = (size_t)NVAL * DM;
  float* ws = (float*)d_ws;
  float* value = ws;
  float* B0   = ws + VAL_F;
  float* qin  = B0 + 0 * S;
  float* Qb   = B0 + 1 * S;
  float* Kb   = B0 + 2 * S;
  float* Vb   = B0 + 3 * S;
  float* Ob   = B0 + 4 * S;
  float* tmp  = B0 + 5 * S;
  float* x1   = B0 + 0 * S;
  float* q2   = B0 + 1 * S;
  float* offb = B0 + 2 * S;
  float* attb = B0 + 3 * S;
  float* samp = B0 + 4 * S;
  float* x2   = B0 + 6 * S;
  float* hffn = B0 + 1 * S;

  const float qscale = 0.17677669529663687f;  // 1/sqrt(32)
  const int n4 = (int)(S / 4);
  const dim3 blk(256);
  const dim3 gAdd((n4 + 255) / 256);
  const dim3 gQ(DM / 64, (MROW + 63) / 64);
  const dim3 gAtt(2, (MROW + 63) / 64);
  const dim3 gVal(DM / 64, (NVAL + 63) / 64);
  const dim3 gF1(DFFN / 64, (MROW + 63) / 64);

  // ---- self-attention ----
  add_kernel<<<gAdd, blk, 0, stream>>>(tgt, qpos, qin, n4);
  gemm_bf16<<<gQ, blk, 0, stream>>>(qin, wq, bq, Qb, MROW, DM, DM, qscale, 0);
  gemm_bf16<<<gQ, blk, 0, stream>>>(qin, wk, bk, Kb, MROW, DM, DM, 1.f, 0);
  gemm_bf16<<<gQ, blk, 0, stream>>>(tgt, wv, bv, Vb, MROW, DM, DM, 1.f, 0);
  attn_mfma<<<dim3((LQ + 63) / 64, NH, NB), blk, 0, stream>>>(Qb, Kb, Vb, Ob);
  gemm_bf16<<<gQ, blk, 0, stream>>>(Ob, wo, bo, tmp, MROW, DM, DM, 1.f, 0);
  ln_kernel<<<dim3(MROW), dim3(64), 0, stream>>>(tmp, tgt, ln2g, ln2b, x1);

  // ---- deformable cross-attention ----
  gemm_bf16<<<gVal, blk, 0, stream>>>(src, w_val, b_val, value, NVAL, DM, DM, 1.f, 0);
  add_kernel<<<gAdd, blk, 0, stream>>>(x1, qpos, q2, n4);
  gemm_bf16<<<gQ, blk, 0, stream>>>(q2, w_off, b_off, offb, MROW, DM, DM, 1.f, 0);
  gemm_bf16<<<gAtt, blk, 0, stream>>>(q2, w_att, b_att, attb, MROW, NH * NL * NP, DM, 1.f, 0);
  softmax16_kernel<<<dim3((MROW * NH + 255) / 256), blk, 0, stream>>>(attb, MROW * NH);
  sample_kernel<<<dim3(MROW), blk, 0, stream>>>(value, ref, offb, attb, samp);
  gemm_bf16<<<gQ, blk, 0, stream>>>(samp, w_out, b_out, tmp, MROW, DM, DM, 1.f, 0);
  ln_kernel<<<dim3(MROW), dim3(64), 0, stream>>>(tmp, x1, ln1g, ln1b, x2);

  // ---- FFN ----
  gemm_bf16<<<gF1, blk, 0, stream>>>(x2, w1, b1, hffn, MROW, DFFN, DM, 1.f, 1);
  gemm_bf16<<<gQ, blk, 0, stream>>>(hffn, w2, b2, tmp, MROW, DM, DFFN, 1.f, 0);
  ln_kernel<<<dim3(MROW), dim3(64), 0, stream>>>(tmp, x2, ln3g, ln3b, (float*)d_out);
}

// Round 4
// 317.992 us; speedup vs baseline: 2.8522x; 1.4161x over previous
//
#include <hip/hip_runtime.h>
#include <math.h>

#define NB 8
#define LQ 900
#define DM 256
#define NH 8
#define DH 32
#define NL 4
#define NP 4
#define DFFN 1024
#define LIN 13294
#define NVAL (NB*LIN)      // 106352 rows for value projection
#define MROW (NB*LQ)       // 7200 rows for query-side matmuls

typedef __attribute__((ext_vector_type(8))) short bf16x8;
typedef __attribute__((ext_vector_type(4))) float f32x4;

__device__ __forceinline__ unsigned short f2bf(float x) {
  unsigned u = __float_as_uint(x);
  u += 0x7FFFu + ((u >> 16) & 1u);   // round-to-nearest-even
  return (unsigned short)(u >> 16);
}

// ---------------- elementwise add (float4) ----------------
__global__ __launch_bounds__(256) void add_kernel(const float* __restrict__ a,
                                                  const float* __restrict__ b,
                                                  float* __restrict__ c, int n4) {
  int i = blockIdx.x * 256 + threadIdx.x;
  if (i < n4) {
    float4 x = ((const float4*)a)[i];
    float4 y = ((const float4*)b)[i];
    ((float4*)c)[i] = make_float4(x.x + y.x, x.y + y.y, x.z + y.z, x.w + y.w);
  }
}

// ---------------- bf16 MFMA GEMM: C = (A@W + bias)*scale, opt relu, opt bf16 out ----------------
#define LDSW 40   // LDS row stride in bf16 elems
__global__ __launch_bounds__(256) void gemm_bf16(const float* __restrict__ A,
                                                 const float* __restrict__ W,
                                                 const float* __restrict__ bias,
                                                 float* __restrict__ C,
                                                 int M, int Nn, int K, float scale, int relu,
                                                 int out_bf16) {
  __shared__ short As[64 * LDSW];
  __shared__ short Bs[64 * LDSW];
  const int tid = threadIdx.x;
  const int lane = tid & 63, w = tid >> 6;
  const int wr = w >> 1, wc = w & 1;
  const int m0 = blockIdx.y << 6, n0 = blockIdx.x << 6;
  const int ar = tid >> 2, ac = (tid & 3) << 3;
  const int bk = tid >> 3, bn = (tid & 7) << 3;
  const int aswz = (((ac >> 3) ^ (ar >> 3)) & 3) << 3;
  const int l15 = lane & 15, lc = lane >> 4;
  f32x4 acc[2][2] = {};
  for (int kt = 0; kt < K; kt += 32) {
    float4 a0 = make_float4(0.f, 0.f, 0.f, 0.f), a1 = a0;
    if (m0 + ar < M) {
      const float* ap = A + (size_t)(m0 + ar) * K + kt + ac;
      a0 = ((const float4*)ap)[0]; a1 = ((const float4*)ap)[1];
    }
    const float* wp = W + (size_t)(kt + bk) * Nn + n0 + bn;
    const float4 b0 = ((const float4*)wp)[0], b1 = ((const float4*)wp)[1];
    __syncthreads();
    {
      bf16x8 av;
      av[0] = (short)f2bf(a0.x); av[1] = (short)f2bf(a0.y);
      av[2] = (short)f2bf(a0.z); av[3] = (short)f2bf(a0.w);
      av[4] = (short)f2bf(a1.x); av[5] = (short)f2bf(a1.y);
      av[6] = (short)f2bf(a1.z); av[7] = (short)f2bf(a1.w);
      *(bf16x8*)&As[ar * LDSW + aswz] = av;
      unsigned short bb[8] = {f2bf(b0.x), f2bf(b0.y), f2bf(b0.z), f2bf(b0.w),
                              f2bf(b1.x), f2bf(b1.y), f2bf(b1.z), f2bf(b1.w)};
      const int bchunk = bk >> 3, bke = bk & 7;
#pragma unroll
      for (int j = 0; j < 8; j++) {
        const int n = bn + j;
        Bs[n * LDSW + (((bchunk ^ (n >> 3)) & 3) << 3) + bke] = (short)bb[j];
      }
    }
    __syncthreads();
    bf16x8 af[2], bf[2];
#pragma unroll
    for (int i = 0; i < 2; i++) {
      const int row = wr * 32 + i * 16 + l15;
      af[i] = *(const bf16x8*)&As[row * LDSW + (((lc ^ (row >> 3)) & 3) << 3)];
      const int col = wc * 32 + i * 16 + l15;
      bf[i] = *(const bf16x8*)&Bs[col * LDSW + (((lc ^ (col >> 3)) & 3) << 3)];
    }
#pragma unroll
    for (int i = 0; i < 2; i++)
#pragma unroll
      for (int j = 0; j < 2; j++)
        acc[i][j] = __builtin_amdgcn_mfma_f32_16x16x32_bf16(af[i], bf[j], acc[i][j], 0, 0, 0);
  }
#pragma unroll
  for (int i = 0; i < 2; i++) {
    const int row0 = m0 + wr * 32 + i * 16 + lc * 4;
#pragma unroll
    for (int j = 0; j < 2; j++) {
      const int col = n0 + wc * 32 + j * 16 + l15;
      const float bv = bias[col];
#pragma unroll
      for (int r = 0; r < 4; r++) {
        const int row = row0 + r;
        if (row < M) {
          float v = (acc[i][j][r] + bv) * scale;
          if (relu) v = fmaxf(v, 0.f);
          if (out_bf16)
            ((unsigned short*)C)[(size_t)row * Nn + col] = f2bf(v);
          else
            C[(size_t)row * Nn + col] = v;
        }
      }
    }
  }
}

// ---------------- MFMA flash attention ----------------
__global__ __launch_bounds__(256) void attn_mfma(const float* __restrict__ Qg,
                                                 const float* __restrict__ Kg,
                                                 const float* __restrict__ Vg,
                                                 float* __restrict__ O) {
  __shared__ short Ks[2048];
  __shared__ short Vt[2048];
  __shared__ short Pl[4096];
  const int tid = threadIdx.x;
  const int lane = tid & 63, w = tid >> 6;
  const int l15 = lane & 15, lc = lane >> 4;
  const int h = blockIdx.y, b = blockIdx.z;
  const int q0 = blockIdx.x * 64;
  char* KsB = (char*)Ks; char* VtB = (char*)Vt; char* PlB = (char*)Pl + w * 2048;

  bf16x8 qa;
  {
    const int qrow = min(q0 + w * 16 + l15, LQ - 1);
    const float* qp = Qg + ((size_t)(b * LQ + qrow)) * DM + h * DH + lc * 8;
    const float4 qx = ((const float4*)qp)[0], qy = ((const float4*)qp)[1];
    qa[0] = (short)f2bf(qx.x); qa[1] = (short)f2bf(qx.y);
    qa[2] = (short)f2bf(qx.z); qa[3] = (short)f2bf(qx.w);
    qa[4] = (short)f2bf(qy.x); qa[5] = (short)f2bf(qy.y);
    qa[6] = (short)f2bf(qy.z); qa[7] = (short)f2bf(qy.w);
  }
  f32x4 o0 = {0.f, 0.f, 0.f, 0.f}, o1 = {0.f, 0.f, 0.f, 0.f};
  float mrow[4], lrow[4];
#pragma unroll
  for (int r = 0; r < 4; r++) { mrow[r] = -1e30f; lrow[r] = 0.f; }
  const int skey = tid >> 2, sq = tid & 3;

  for (int kt = 0; kt < LQ; kt += 64) {
    const int kr = min(kt + skey, LQ - 1);
    const float* kp = Kg + ((size_t)(b * LQ + kr)) * DM + h * DH + sq * 8;
    const float* vp = Vg + ((size_t)(b * LQ + kr)) * DM + h * DH + sq * 8;
    const float4 k0 = ((const float4*)kp)[0], k1 = ((const float4*)kp)[1];
    const float4 v0 = ((const float4*)vp)[0], v1 = ((const float4*)vp)[1];
    __syncthreads();
    {
      bf16x8 kb;
      kb[0] = (short)f2bf(k0.x); kb[1] = (short)f2bf(k0.y);
      kb[2] = (short)f2bf(k0.z); kb[3] = (short)f2bf(k0.w);
      kb[4] = (short)f2bf(k1.x); kb[5] = (short)f2bf(k1.y);
      kb[6] = (short)f2bf(k1.z); kb[7] = (short)f2bf(k1.w);
      *(bf16x8*)(KsB + ((skey * 64 + sq * 16) ^ ((skey & 7) << 4))) = kb;
      unsigned short vv[8] = {f2bf(v0.x), f2bf(v0.y), f2bf(v0.z), f2bf(v0.w),
                              f2bf(v1.x), f2bf(v1.y), f2bf(v1.z), f2bf(v1.w)};
#pragma unroll
      for (int j = 0; j < 8; j++) {
        const int dh = sq * 8 + j;
        const int qz = ((dh & 7) ^ (((dh >> 3) & 3) << 1)) << 4;
        *(short*)(VtB + ((dh * 128 + skey * 2) ^ qz)) = (short)vv[j];
      }
    }
    __syncthreads();
    f32x4 s[4];
#pragma unroll
    for (int cb = 0; cb < 4; cb++) {
      const int key = cb * 16 + l15;
      const bf16x8 kf = *(const bf16x8*)(KsB + ((key * 64 + lc * 16) ^ ((key & 7) << 4)));
      const f32x4 z = {0.f, 0.f, 0.f, 0.f};
      s[cb] = __builtin_amdgcn_mfma_f32_16x16x32_bf16(qa, kf, z, 0, 0, 0);
    }
#pragma unroll
    for (int cb = 0; cb < 4; cb++)
      if (kt + cb * 16 + l15 >= LQ) {
        s[cb][0] = -1e30f; s[cb][1] = -1e30f; s[cb][2] = -1e30f; s[cb][3] = -1e30f;
      }
    float tm[4], fs[4], ps[4];
#pragma unroll
    for (int r = 0; r < 4; r++)
      tm[r] = fmaxf(fmaxf(s[0][r], s[1][r]), fmaxf(s[2][r], s[3][r]));
#pragma unroll
    for (int msk = 1; msk <= 8; msk <<= 1)
#pragma unroll
      for (int r = 0; r < 4; r++) tm[r] = fmaxf(tm[r], __shfl_xor(tm[r], msk));
#pragma unroll
    for (int r = 0; r < 4; r++) {
      const float nm = fmaxf(mrow[r], tm[r]);
      fs[r] = __expf(mrow[r] - nm);
      mrow[r] = nm;
    }
#pragma unroll
    for (int cb = 0; cb < 4; cb++)
#pragma unroll
      for (int r = 0; r < 4; r++) s[cb][r] = __expf(s[cb][r] - mrow[r]);
#pragma unroll
    for (int r = 0; r < 4; r++) ps[r] = (s[0][r] + s[1][r]) + (s[2][r] + s[3][r]);
#pragma unroll
    for (int msk = 1; msk <= 8; msk <<= 1)
#pragma unroll
      for (int r = 0; r < 4; r++) ps[r] += __shfl_xor(ps[r], msk);
#pragma unroll
    for (int r = 0; r < 4; r++) {
      lrow[r] = lrow[r] * fs[r] + ps[r];
      o0[r] *= fs[r]; o1[r] *= fs[r];
    }
#pragma unroll
    for (int cb = 0; cb < 4; cb++)
#pragma unroll
      for (int r = 0; r < 4; r++) {
        const int row = lc * 4 + r, col = cb * 16 + l15;
        *(short*)(PlB + ((row * 128 + col * 2) ^ ((row & 7) << 4))) = (short)f2bf(s[cb][r]);
      }
#pragma unroll
    for (int ks2 = 0; ks2 < 2; ks2++) {
      const int koff2 = (ks2 * 32 + lc * 8) * 2;
      const bf16x8 pa = *(const bf16x8*)(PlB + ((l15 * 128 + koff2) ^ ((l15 & 7) << 4)));
      {
        const int dh = l15;
        const int qz = ((dh & 7) ^ (((dh >> 3) & 3) << 1)) << 4;
        const bf16x8 vf = *(const bf16x8*)(VtB + ((dh * 128 + koff2) ^ qz));
        o0 = __builtin_amdgcn_mfma_f32_16x16x32_bf16(pa, vf, o0, 0, 0, 0);
      }
      {
        const int dh = 16 + l15;
        const int qz = ((dh & 7) ^ (((dh >> 3) & 3) << 1)) << 4;
        const bf16x8 vf = *(const bf16x8*)(VtB + ((dh * 128 + koff2) ^ qz));
        o1 = __builtin_amdgcn_mfma_f32_16x16x32_bf16(pa, vf, o1, 0, 0, 0);
      }
    }
  }
#pragma unroll
  for (int r = 0; r < 4; r++) {
    const int qrow = q0 + w * 16 + lc * 4 + r;
    if (qrow < LQ) {
      const float inv = 1.f / lrow[r];
      float* op = O + ((size_t)(b * LQ + qrow)) * DM + h * DH;
      op[l15] = o0[r] * inv;
      op[16 + l15] = o1[r] * inv;
    }
  }
}

// ---------------- MS-deform sampling: 4 threads per (b,q,h), 8 channels each ----------------
// value: (N, LIN, 256) bf16; ref: (N,LQ,4,2); off: (N,LQ,256); att: (N,LQ,128) RAW logits
// out: (N,LQ,256). t = ((b*LQ+q)*8 + h)*4 + d8; thread covers channels d8*8..d8*8+7.
__global__ __launch_bounds__(256) void sample_kernel(const unsigned short* __restrict__ value,
                                                     const float* __restrict__ ref,
                                                     const float* __restrict__ off,
                                                     const float* __restrict__ att,
                                                     float* __restrict__ out) {
  const int t = blockIdx.x * 256 + threadIdx.x;   // < NB*LQ*NH*4 = 230400
  const int d8 = t & 3;
  const int h = (t >> 2) & 7;
  const int qb = t >> 5;                           // b*LQ + q
  const int b = qb / LQ;
  const int HLs[4] = {100, 50, 25, 13};
  const int STs[4] = {0, 10000, 12500, 13125};
  const float* rp = ref + (size_t)qb * (NL * 2);
  const float* op = off + (size_t)qb * DM + h * (NL * NP * 2);
  const float* ap = att + (size_t)qb * (NH * NL * NP) + h * (NL * NP);
  const unsigned short* vb = value + (size_t)b * LIN * DM + h * DH + d8 * 8;

  // fused softmax over the 16 attention logits
  float aw[16];
#pragma unroll
  for (int i = 0; i < 4; i++) {
    const float4 a4 = ((const float4*)ap)[i];
    aw[4 * i] = a4.x; aw[4 * i + 1] = a4.y; aw[4 * i + 2] = a4.z; aw[4 * i + 3] = a4.w;
  }
  float am = aw[0];
#pragma unroll
  for (int i = 1; i < 16; i++) am = fmaxf(am, aw[i]);
  float asum = 0.f;
#pragma unroll
  for (int i = 0; i < 16; i++) { aw[i] = __expf(aw[i] - am); asum += aw[i]; }
  const float ainv = 1.f / asum;

  float acc[8] = {};
#pragma unroll
  for (int l = 0; l < NL; l++) {
    const int Hl = HLs[l], Wl = HLs[l], st = STs[l];
    const float rx = rp[l * 2], ry = rp[l * 2 + 1];
#pragma unroll
    for (int p = 0; p < NP; p++) {
      const float2 o2 = ((const float2*)op)[l * NP + p];
      const float a = aw[l * NP + p] * ainv;
      const float locx = rx + o2.x / (float)Wl;
      const float locy = ry + o2.y / (float)Hl;
      const float x = locx * (float)Wl - 0.5f;
      const float y = locy * (float)Hl - 0.5f;
      const float xf = floorf(x), yf = floorf(y);
      const float fx = x - xf, fy = y - yf;
      const int x0 = (int)xf, y0 = (int)yf;
      const int x1 = x0 + 1, y1 = y0 + 1;
      const float vx0 = (x0 >= 0 && x0 < Wl) ? 1.f : 0.f;
      const float vx1 = (x1 >= 0 && x1 < Wl) ? 1.f : 0.f;
      const float vy0 = (y0 >= 0 && y0 < Hl) ? 1.f : 0.f;
      const float vy1 = (y1 >= 0 && y1 < Hl) ? 1.f : 0.f;
      const int cx0 = min(max(x0, 0), Wl - 1), cx1 = min(max(x1, 0), Wl - 1);
      const int cy0 = min(max(y0, 0), Hl - 1), cy1 = min(max(y1, 0), Hl - 1);
      const float w00 = a * (1.f - fx) * (1.f - fy) * vx0 * vy0;
      const float w10 = a * fx * (1.f - fy) * vx1 * vy0;
      const float w01 = a * (1.f - fx) * fy * vx0 * vy1;
      const float w11 = a * fx * fy * vx1 * vy1;
      const unsigned short* r0 = vb + (size_t)(st + cy0 * Wl) * DM;
      const unsigned short* r1 = vb + (size_t)(st + cy1 * Wl) * DM;
      const uint4 g00 = *(const uint4*)(r0 + (size_t)cx0 * DM);
      const uint4 g10 = *(const uint4*)(r0 + (size_t)cx1 * DM);
      const uint4 g01 = *(const uint4*)(r1 + (size_t)cx0 * DM);
      const uint4 g11 = *(const uint4*)(r1 + (size_t)cx1 * DM);
      const unsigned u00[4] = {g00.x, g00.y, g00.z, g00.w};
      const unsigned u10[4] = {g10.x, g10.y, g10.z, g10.w};
      const unsigned u01[4] = {g01.x, g01.y, g01.z, g01.w};
      const unsigned u11[4] = {g11.x, g11.y, g11.z, g11.w};
#pragma unroll
      for (int i = 0; i < 4; i++) {
        acc[2 * i]     += w00 * __uint_as_float(u00[i] << 16) + w10 * __uint_as_float(u10[i] << 16)
                        + w01 * __uint_as_float(u01[i] << 16) + w11 * __uint_as_float(u11[i] << 16);
        acc[2 * i + 1] += w00 * __uint_as_float(u00[i] & 0xFFFF0000u) + w10 * __uint_as_float(u10[i] & 0xFFFF0000u)
                        + w01 * __uint_as_float(u01[i] & 0xFFFF0000u) + w11 * __uint_as_float(u11[i] & 0xFFFF0000u);
      }
    }
  }
  float* o = out + (size_t)t * 8;
  *(float4*)o = make_float4(acc[0], acc[1], acc[2], acc[3]);
  *(float4*)(o + 4) = make_float4(acc[4], acc[5], acc[6], acc[7]);
}

// ---------------- fused residual-add + LayerNorm, wave per row ----------------
__global__ __launch_bounds__(64) void ln_kernel(const float* __restrict__ A,
                                                const float* __restrict__ R,
                                                const float* __restrict__ g,
                                                const float* __restrict__ be,
                                                float* __restrict__ out) {
  const int row = blockIdx.x, t = threadIdx.x;
  const float4 va = ((const float4*)(A + (size_t)row * DM))[t];
  const float4 vr = ((const float4*)(R + (size_t)row * DM))[t];
  const float x0 = va.x + vr.x, x1 = va.y + vr.y, x2 = va.z + vr.z, x3 = va.w + vr.w;
  float s = x0 + x1 + x2 + x3;
  float ss = x0 * x0 + x1 * x1 + x2 * x2 + x3 * x3;
#pragma unroll
  for (int o = 1; o < 64; o <<= 1) { s += __shfl_xor(s, o); ss += __shfl_xor(ss, o); }
  const float mean = s * (1.f / DM);
  const float var = ss * (1.f / DM) - mean * mean;
  const float rstd = rsqrtf(var + 1e-5f);
  const float4 vg = ((const float4*)g)[t];
  const float4 vb = ((const float4*)be)[t];
  float4 o4;
  o4.x = (x0 - mean) * rstd * vg.x + vb.x;
  o4.y = (x1 - mean) * rstd * vg.y + vb.y;
  o4.z = (x2 - mean) * rstd * vg.z + vb.z;
  o4.w = (x3 - mean) * rstd * vg.w + vb.w;
  ((float4*)(out + (size_t)row * DM))[t] = o4;
}

extern "C" void kernel_launch(void* const* d_in, const int* in_sizes, int n_in,
                              void* d_out, int out_size, void* d_ws, size_t ws_size,
                              hipStream_t stream) {
  const float* tgt  = (const float*)d_in[1];
  const float* qpos = (const float*)d_in[2];
  const float* ref  = (const float*)d_in[3];
  const float* src  = (const float*)d_in[4];
  const float* wq = (const float*)d_in[8];  const float* bq = (const float*)d_in[9];
  const float* wk = (const float*)d_in[10]; const float* bk = (const float*)d_in[11];
  const float* wv = (const float*)d_in[12]; const float* bv = (const float*)d_in[13];
  const float* wo = (const float*)d_in[14]; const float* bo = (const float*)d_in[15];
  const float* w_val = (const float*)d_in[16]; const float* b_val = (const float*)d_in[17];
  const float* w_off = (const float*)d_in[18]; const float* b_off = (const float*)d_in[19];
  const float* w_att = (const float*)d_in[20]; const float* b_att = (const float*)d_in[21];
  const float* w_out = (const float*)d_in[22]; const float* b_out = (const float*)d_in[23];
  const float* ln1g = (const float*)d_in[24]; const float* ln1b = (const float*)d_in[25];
  const float* ln2g = (const float*)d_in[26]; const float* ln2b = (const float*)d_in[27];
  const float* ln3g = (const float*)d_in[28]; const float* ln3b = (const float*)d_in[29];
  const float* w1 = (const float*)d_in[30]; const float* b1 = (const float*)d_in[31];
  const float* w2 = (const float*)d_in[32]; const float* b2 = (const float*)d_in[33];

  const size_t S = (size_t)MROW * DM;
  const size_t VAL_F = (size_t)NVAL * DM;
  float* ws = (float*)d_ws;
  float* value = ws;                 // bf16 now: uses half this span
  float* B0   = ws + VAL_F;
  float* qin  = B0 + 0 * S;
  float* Qb   = B0 + 1 * S;
  float* Kb   = B0 + 2 * S;
  float* Vb   = B0 + 3 * S;
  float* Ob   = B0 + 4 * S;
  float* tmp  = B0 + 5 * S;
  float* x1   = B0 + 0 * S;
  float* q2   = B0 + 1 * S;
  float* offb = B0 + 2 * S;
  float* attb = B0 + 3 * S;
  float* samp = B0 + 4 * S;
  float* x2   = B0 + 6 * S;
  float* hffn = B0 + 1 * S;

  const float qscale = 0.17677669529663687f;  // 1/sqrt(32)
  const int n4 = (int)(S / 4);
  const dim3 blk(256);
  const dim3 gAdd((n4 + 255) / 256);
  const dim3 gQ(DM / 64, (MROW + 63) / 64);
  const dim3 gAtt(2, (MROW + 63) / 64);
  const dim3 gVal(DM / 64, (NVAL + 63) / 64);
  const dim3 gF1(DFFN / 64, (MROW + 63) / 64);

  // ---- self-attention ----
  add_kernel<<<gAdd, blk, 0, stream>>>(tgt, qpos, qin, n4);
  gemm_bf16<<<gQ, blk, 0, stream>>>(qin, wq, bq, Qb, MROW, DM, DM, qscale, 0, 0);
  gemm_bf16<<<gQ, blk, 0, stream>>>(qin, wk, bk, Kb, MROW, DM, DM, 1.f, 0, 0);
  gemm_bf16<<<gQ, blk, 0, stream>>>(tgt, wv, bv, Vb, MROW, DM, DM, 1.f, 0, 0);
  attn_mfma<<<dim3((LQ + 63) / 64, NH, NB), blk, 0, stream>>>(Qb, Kb, Vb, Ob);
  gemm_bf16<<<gQ, blk, 0, stream>>>(Ob, wo, bo, tmp, MROW, DM, DM, 1.f, 0, 0);
  ln_kernel<<<dim3(MROW), dim3(64), 0, stream>>>(tmp, tgt, ln2g, ln2b, x1);

  // ---- deformable cross-attention ----
  gemm_bf16<<<gVal, blk, 0, stream>>>(src, w_val, b_val, value, NVAL, DM, DM, 1.f, 0, 1);
  add_kernel<<<gAdd, blk, 0, stream>>>(x1, qpos, q2, n4);
  gemm_bf16<<<gQ, blk, 0, stream>>>(q2, w_off, b_off, offb, MROW, DM, DM, 1.f, 0, 0);
  gemm_bf16<<<gAtt, blk, 0, stream>>>(q2, w_att, b_att, attb, MROW, NH * NL * NP, DM, 1.f, 0, 0);
  sample_kernel<<<dim3((MROW * NH * 4) / 256), blk, 0, stream>>>(
      (const unsigned short*)value, ref, offb, attb, samp);
  gemm_bf16<<<gQ, blk, 0, stream>>>(samp, w_out, b_out, tmp, MROW, DM, DM, 1.f, 0, 0);
  ln_kernel<<<dim3(MROW), dim3(64), 0, stream>>>(tmp, x1, ln1g, ln1b, x2);

  // ---- FFN ----
  gemm_bf16<<<gF1, blk, 0, stream>>>(x2, w1, b1, hffn, MROW, DFFN, DM, 1.f, 1, 0);
  gemm_bf16<<<gQ, blk, 0, stream>>>(hffn, w2, b2, tmp, MROW, DM, DFFN, 1.f, 0, 0);
  ln_kernel<<<dim3(MROW), dim3(64), 0, stream>>>(tmp, x2, ln3g, ln3b, (float*)d_out);
}